// Round 7
// baseline (206.034 us; speedup 1.0000x reference)
//
#include <hip/hip_runtime.h>

typedef float f32x4 __attribute__((ext_vector_type(4)));
typedef __bf16 v8bf __attribute__((ext_vector_type(8)));
typedef unsigned int u32x2 __attribute__((ext_vector_type(2)));

#define B_ 8
#define N_ 4096
#define C_ 192
#define H_ 768
#define NP_ 4352   // hb row pitch in elements (8704 B = 8.5 KB, breaks pow2 stride)

__device__ __forceinline__ unsigned short f2bf(float f) {
  unsigned int u = __float_as_uint(f);
  u += 0x7FFFu + ((u >> 16) & 1u);          // RNE
  return (unsigned short)(u >> 16);
}
__device__ __forceinline__ unsigned int pk2(float lo, float hi) {
  return (unsigned int)f2bf(lo) | ((unsigned int)f2bf(hi) << 16);
}
__device__ __forceinline__ void unpk(unsigned int w, float& a, float& b) {
  a = __uint_as_float(w << 16);
  b = __uint_as_float(w & 0xFFFF0000u);
}

#define LDS_AS(p) ((__attribute__((address_space(3))) unsigned int*)(void*)(p))
__device__ __forceinline__ void gld16(const void* g, void* l) {
  __builtin_amdgcn_global_load_lds((const __attribute__((address_space(1))) unsigned int*)g,
                                   LDS_AS(l), 16, 0, 0);
}
__device__ __forceinline__ unsigned ldsoff(const void* p) {
  return (unsigned)(size_t)((__attribute__((address_space(3))) char*)(void*)p);
}

// ---------------------------------------------------------------- gemm1
// hb[b][h][n] = relu(bn1( sum_c x[b][n][c] * W1[h][c] ))   (bf16 out, pitched)
__global__ __launch_bounds__(256) void gemm1k(
    const float* __restrict__ x, const float* __restrict__ W1,
    const float* __restrict__ g1, const float* __restrict__ b1,
    const float* __restrict__ m1, const float* __restrict__ v1,
    unsigned short* __restrict__ hb) {
  __shared__ __align__(16) unsigned short pool[18432];   // 36864 B
  unsigned short* As = pool;            // [128 n][72 pitch] (cols c)
  unsigned short* Bs = pool + 9216;     // [128 h][72 pitch]
  unsigned short* Ts = pool;            // epilogue alias: [128 h][136 pitch n]
  const int n0 = blockIdx.x << 7, h0 = blockIdx.y << 7, b = blockIdx.z;
  const int tid = threadIdx.x;
  const int l = tid & 63, q = l >> 4, l16 = l & 15;
  const int wv = tid >> 6, wr = wv >> 1, wc = wv & 1;
  const int srow = tid >> 3, scol = (tid & 7) << 3;
  f32x4 acc[4][4];
#pragma unroll
  for (int i_ = 0; i_ < 4; ++i_)
#pragma unroll
    for (int j_ = 0; j_ < 4; ++j_) acc[i_][j_] = {0.f, 0.f, 0.f, 0.f};

  for (int kt = 0; kt < 3; ++kt) {
    const int c0 = kt << 6;
#pragma unroll
    for (int p = 0; p < 4; ++p) {
      int row = srow + (p << 5);
      const float4* sa = reinterpret_cast<const float4*>(
          &x[(size_t)(b * N_ + n0 + row) * C_ + c0 + scol]);
      float4 a0 = sa[0], a1 = sa[1];
      uint4 w;
      w.x = pk2(a0.x, a0.y); w.y = pk2(a0.z, a0.w);
      w.z = pk2(a1.x, a1.y); w.w = pk2(a1.z, a1.w);
      *reinterpret_cast<uint4*>(&As[row * 72 + scol]) = w;
      const float4* sb = reinterpret_cast<const float4*>(
          &W1[(size_t)(h0 + row) * C_ + c0 + scol]);
      float4 b0 = sb[0], b1_ = sb[1];
      uint4 u;
      u.x = pk2(b0.x, b0.y); u.y = pk2(b0.z, b0.w);
      u.z = pk2(b1_.x, b1_.y); u.w = pk2(b1_.z, b1_.w);
      *reinterpret_cast<uint4*>(&Bs[row * 72 + scol]) = u;
    }
    __syncthreads();
#pragma unroll
    for (int ks = 0; ks < 2; ++ks) {
      v8bf av[4], bv[4];
#pragma unroll
      for (int f = 0; f < 4; ++f)
        av[f] = *reinterpret_cast<const v8bf*>(&As[((wr << 6) + (f << 4) + l16) * 72 + (ks << 5) + (q << 3)]);
#pragma unroll
      for (int f = 0; f < 4; ++f)
        bv[f] = *reinterpret_cast<const v8bf*>(&Bs[((wc << 6) + (f << 4) + l16) * 72 + (ks << 5) + (q << 3)]);
#pragma unroll
      for (int fm = 0; fm < 4; ++fm)
#pragma unroll
        for (int fn = 0; fn < 4; ++fn)
          acc[fm][fn] = __builtin_amdgcn_mfma_f32_16x16x32_bf16(av[fm], bv[fn], acc[fm][fn], 0, 0, 0);
    }
    __syncthreads();
  }
  // epilogue: BN+ReLU -> bf16 into Ts[h][n] (pitch 136), then coalesced copy-out
#pragma unroll
  for (int fn = 0; fn < 4; ++fn) {
    int hl = (wc << 6) + (fn << 4) + l16;
    int hh = h0 + hl;
    float s = g1[hh] * rsqrtf(v1[hh] + 1e-5f);
    float bias = b1[hh] - m1[hh] * s;
#pragma unroll
    for (int fm = 0; fm < 4; ++fm) {
      int nl = (wr << 6) + (fm << 4) + (q << 2);
      ushort4 o;
      o.x = f2bf(fmaxf(acc[fm][fn][0] * s + bias, 0.f));
      o.y = f2bf(fmaxf(acc[fm][fn][1] * s + bias, 0.f));
      o.z = f2bf(fmaxf(acc[fm][fn][2] * s + bias, 0.f));
      o.w = f2bf(fmaxf(acc[fm][fn][3] * s + bias, 0.f));
      *reinterpret_cast<ushort4*>(&Ts[hl * 136 + nl]) = o;
    }
  }
  __syncthreads();
  {
    const int rq = tid >> 4, ch = (tid & 15) << 3;
#pragma unroll
    for (int p = 0; p < 8; ++p) {
      int r = (p << 4) + rq;
      uint4 v = *reinterpret_cast<const uint4*>(&Ts[r * 136 + ch]);
      *reinterpret_cast<uint4*>(&hb[(size_t)(b * H_ + h0 + r) * NP_ + n0 + ch]) = v;
    }
  }
}

// ---------------------------------------------------------------- FFT pieces
template <bool INV>
__device__ __forceinline__ void dft4(float& ar, float& ai, float& br, float& bi,
                                     float& cr, float& ci, float& dr, float& di) {
  float t0r = ar + cr, t0i = ai + ci;
  float t1r = ar - cr, t1i = ai - ci;
  float t2r = br + dr, t2i = bi + di;
  float t3r = br - dr, t3i = bi - di;
  ar = t0r + t2r; ai = t0i + t2i;
  cr = t0r - t2r; ci = t0i - t2i;
  if (!INV) { br = t1r + t3i; bi = t1i - t3r; dr = t1r - t3i; di = t1i + t3r; }
  else      { br = t1r - t3i; bi = t1i + t3r; dr = t1r + t3i; di = t1i - t3r; }
}
template <bool INV>
__device__ __forceinline__ void twc(float& xr, float& xi, float wr, float wi) {
  float iw = INV ? -wi : wi;
  float nr = xr * wr - xi * iw;
  xi = xr * iw + xi * wr;
  xr = nr;
}
template <bool INV>
__device__ __forceinline__ void fft16(float* xr, float* xi) {
#pragma unroll
  for (int j = 0; j < 4; ++j)
    dft4<INV>(xr[j], xi[j], xr[j + 4], xi[j + 4], xr[j + 8], xi[j + 8], xr[j + 12], xi[j + 12]);
  const float C1 = 0.9238795325112867f, S1 = -0.3826834323650898f;
  const float C2 = 0.7071067811865476f, S2 = -0.7071067811865476f;
  twc<INV>(xr[5], xi[5], C1, S1);
  twc<INV>(xr[6], xi[6], C2, S2);
  twc<INV>(xr[9], xi[9], C2, S2);
  twc<INV>(xr[7], xi[7], -S1, -C1);
  twc<INV>(xr[13], xi[13], -S1, -C1);
  twc<INV>(xr[10], xi[10], 0.f, -1.f);
  twc<INV>(xr[11], xi[11], -C2, S2);
  twc<INV>(xr[14], xi[14], -C2, S2);
  twc<INV>(xr[15], xi[15], -C1, -S1);
  float yr[16], yi[16];
#pragma unroll
  for (int k = 0; k < 4; ++k) {
    float ar = xr[4 * k], ai = xi[4 * k], br = xr[4 * k + 1], bi = xi[4 * k + 1];
    float cr = xr[4 * k + 2], ci = xi[4 * k + 2], dr = xr[4 * k + 3], di = xi[4 * k + 3];
    dft4<INV>(ar, ai, br, bi, cr, ci, dr, di);
    yr[k] = ar; yi[k] = ai; yr[k + 4] = br; yi[k + 4] = bi;
    yr[k + 8] = cr; yi[k + 8] = ci; yr[k + 12] = dr; yi[k + 12] = di;
  }
#pragma unroll
  for (int qq = 0; qq < 16; ++qq) { xr[qq] = yr[qq]; xi[qq] = yi[qq]; }
}
template <bool INV>
__device__ __forceinline__ void fft8(float* xr, float* xi) {
  float er[4] = {xr[0], xr[2], xr[4], xr[6]}, ei[4] = {xi[0], xi[2], xi[4], xi[6]};
  float o_r[4] = {xr[1], xr[3], xr[5], xr[7]}, o_i[4] = {xi[1], xi[3], xi[5], xi[7]};
  dft4<INV>(er[0], ei[0], er[1], ei[1], er[2], ei[2], er[3], ei[3]);
  dft4<INV>(o_r[0], o_i[0], o_r[1], o_i[1], o_r[2], o_i[2], o_r[3], o_i[3]);
  const float c = 0.7071067811865476f;
  twc<INV>(o_r[1], o_i[1], c, -c);      // W8^1
  twc<INV>(o_r[2], o_i[2], 0.f, -1.f);  // W8^2
  twc<INV>(o_r[3], o_i[3], -c, -c);     // W8^3
#pragma unroll
  for (int k = 0; k < 4; ++k) {
    xr[k] = er[k] + o_r[k]; xi[k] = ei[k] + o_i[k];
    xr[k + 4] = er[k] - o_r[k]; xi[k + 4] = ei[k] - o_i[k];
  }
}
template <bool INV>
__device__ __forceinline__ void twchain(float* xr, float* xi, int j, float invL) {
  float ang = -6.283185307179586f * (float)j * invL;
  if (INV) ang = -ang;
  float s1, c1;
  __sincosf(ang, &s1, &c1);
  float wr = c1, wi = s1;
#pragma unroll
  for (int r2 = 1; r2 < 16; ++r2) {
    float nr = xr[r2] * wr - xi[r2] * wi;
    xi[r2] = xr[r2] * wi + xi[r2] * wr;
    xr[r2] = nr;
    float t2 = wr * c1 - wi * s1;
    wi = wr * s1 + wi * c1;
    wr = t2;
  }
}

// one packed bin-pair of the frequency-domain op:
// inputs Zk=Z[k], Zp=Z[(2048-k)&2047], W=e^{-2pi i k/4096}; outputs G[k], G[2048-k]
// (valid for all k in [0,2048); self-pairs give G1==G2)
__device__ __forceinline__ void mixpair(float2 Zk, float2 Zp, float wr, float wi,
                                        float dr, float di, float rbh, float ibh,
                                        float2& G1, float2& G2) {
  const float sc = 0.015625f;
  float Er = 0.5f * (Zk.x + Zp.x), Ei = 0.5f * (Zk.y - Zp.y);
  float Or = 0.5f * (Zk.y + Zp.y), Oi = 0.5f * (Zp.x - Zk.x);
  float WOr = wr * Or - wi * Oi, WOi = wr * Oi + wi * Or;
  float X1r = Er + WOr, X1i = Ei + WOi;   // bin k
  float X2r = Er - WOr, X2i = Ei - WOi;   // bin k+2048
  float p1 = dr * X1r * sc, p2 = di * X1i * sc, p3 = dr * X1i * sc, p4 = di * X1r * sc;
  float y1r = fmaxf(p1 - p2 + rbh, 0.f), y1i = fmaxf(p3 + p4 + ibh, 0.f);   // Y[k]
  float y4r = fmaxf(p1 + p2 + rbh, 0.f), y4i = fmaxf(p4 - p3 + ibh, 0.f);   // Y[4096-k]
  float q1 = dr * X2r * sc, q2 = di * X2i * sc, q3 = dr * X2i * sc, q4 = di * X2r * sc;
  float y2r = fmaxf(q1 - q2 + rbh, 0.f), y2i = fmaxf(q3 + q4 + ibh, 0.f);   // Y[k+2048]
  float y3r = fmaxf(q1 + q2 + rbh, 0.f), y3i = fmaxf(q4 - q3 + ibh, 0.f);   // Y[2048-k]
  float Hkr = 0.5f * (y1r + y4r), Hki = 0.5f * (y1i - y4i);   // H[k]
  float H2r = 0.5f * (y2r + y3r), H2i = 0.5f * (y2i - y3i);   // H[k+2048]
  float Sr = Hkr + H2r, Si = Hki + H2i;
  float Dr = Hkr - H2r, Di = Hki - H2i;
  float P = wi * Dr - wr * Di, Q = wr * Dr + wi * Di;
  G1 = make_float2(Sr + P, Si + Q);
  G2 = make_float2(Sr - P, Q - Si);
}
__device__ __forceinline__ void rotE8(float& wr, float& wi) {
  const float ER = 0.9238795325112867f, EI = -0.3826834323650898f;  // e^{-i pi/8}
  float t = wr * ER - wi * EI;
  wi = wr * EI + wi * ER;
  wr = t;
}

// ---------------------------------------------------------------- fftmix
// packed real FFT (2048-pt), pair-local mix: stage3-fwd + mix + stage3-inv fully
// in registers (thread owns the Hermitian-partner group pair). 8 LDS passes, 4 barriers.
#define PIDX(i) ((i) + ((i) >> 4))
__global__ __launch_bounds__(256) void fftmixk(
    unsigned short* __restrict__ hb, const float* __restrict__ Rm,
    const float* __restrict__ Im, const float* __restrict__ rb,
    const float* __restrict__ ib) {
  __shared__ float2 cxs[4352];              // 2 channels x 2176 padded float2
  const int b = blockIdx.y;
  const int tid = threadIdx.x;
  const int ch = tid >> 7, j = tid & 127;
  const int h = (blockIdx.x << 1) | ch;
  const int cb = ch * 2176;
  unsigned short* sig = hb + (size_t)(b * H_ + h) * NP_;
  const unsigned int* sig32 = reinterpret_cast<const unsigned int*>(sig);
  unsigned int* o32 = reinterpret_cast<unsigned int*>(sig);

  float xr[16], xi[16];
  // ---- fwd stage 1 (L=2048 radix-16 stride-128): z[m]=h[2m]+i h[2m+1] from global
#pragma unroll
  for (int s = 0; s < 16; ++s) {
    unsigned int w = sig32[j + (s << 7)];
    unpk(w, xr[s], xi[s]);
  }
  fft16<false>(xr, xi);
  twchain<false>(xr, xi, j, 1.0f / 2048.0f);
#pragma unroll
  for (int s = 0; s < 16; ++s) cxs[cb + PIDX(j + (s << 7))] = make_float2(xr[s], xi[s]);
  __syncthreads();
  // ---- fwd stage 2 (128 = 16x8), in-place on own 16 slots
  const int c2 = j >> 3, j2 = j & 7;
#pragma unroll
  for (int s = 0; s < 16; ++s) {
    float2 v = cxs[cb + PIDX((c2 << 7) + j2 + (s << 3))];
    xr[s] = v.x; xi[s] = v.y;
  }
  fft16<false>(xr, xi);
  twchain<false>(xr, xi, j2, 1.0f / 128.0f);
#pragma unroll
  for (int s = 0; s < 16; ++s) cxs[cb + PIDX((c2 << 7) + j2 + (s << 3))] = make_float2(xr[s], xi[s]);
  __syncthreads();
  // ---- stage 3 fwd + mix + stage 3 inv, all registers.
  // group g holds bins kb+256*m3, kb=(g>>4)+16*(g&15); thread owns the pair
  // of groups with kbB = 256-kbA (plus the two self-paired groups on j==0).
  int gA, gB;
  if (j == 0)       { gA = 0;       gB = 8;       }
  else if (j < 8)   { gA = j;       gB = 16 - j;  }
  else if (j < 16)  { gA = 120 + j; gB = 151 - j; }
  else              { gA = j;       gB = 271 - j; }
  const int pA = cb + (gA << 3) + (gA >> 1);   // PIDX(8*gA) .. contiguous 8
  const int pB = cb + (gB << 3) + (gB >> 1);
#pragma unroll
  for (int t = 0; t < 8; ++t) { float2 v = cxs[pA + t]; xr[t] = v.x; xi[t] = v.y; }
#pragma unroll
  for (int t = 0; t < 8; ++t) { float2 v = cxs[pB + t]; xr[8 + t] = v.x; xi[8 + t] = v.y; }
  fft8<false>(xr, xi);
  fft8<false>(xr + 8, xi + 8);
  {
    const float dr = Rm[(size_t)h * (H_ + 1)];
    const float di = Im[(size_t)h * (H_ + 1)];
    const float rbh = rb[h], ibh = ib[h];
    if (j == 0) {
      // group 0 (kb=0): bins 256*m3, pair m3 <-> (8-m3)&7; W^(256m3)=e^{-i pi m3/8}
      float wr = 1.f, wi = 0.f;
#pragma unroll
      for (int m3 = 0; m3 <= 4; ++m3) {
        int p = (8 - m3) & 7;
        float2 G1, G2;
        mixpair(make_float2(xr[m3], xi[m3]), make_float2(xr[p], xi[p]),
                wr, wi, dr, di, rbh, ibh, G1, G2);
        xr[m3] = G1.x; xi[m3] = G1.y; xr[p] = G2.x; xi[p] = G2.y;
        rotE8(wr, wi);
      }
      // group 8 (kb=128): pair m3 <-> 7-m3; W^128 = e^{-i pi/16}
      wr = 0.9807852804032304f; wi = -0.19509032201612825f;
#pragma unroll
      for (int m3 = 0; m3 < 4; ++m3) {
        int p = 15 - m3;
        float2 G1, G2;
        mixpair(make_float2(xr[8 + m3], xi[8 + m3]), make_float2(xr[p], xi[p]),
                wr, wi, dr, di, rbh, ibh, G1, G2);
        xr[8 + m3] = G1.x; xi[8 + m3] = G1.y; xr[p] = G2.x; xi[p] = G2.y;
        rotE8(wr, wi);
      }
    } else {
      int kbA = (gA >> 4) + ((gA & 15) << 4);
      float sn, cs;
      __sincosf((float)kbA * 1.5339807878856412e-3f, &sn, &cs);  // pi/2048
      float wr = cs, wi = -sn;                                    // W^kbA
#pragma unroll
      for (int m3 = 0; m3 < 8; ++m3) {
        int p = 15 - m3;   // B slot 7-m3
        float2 G1, G2;
        mixpair(make_float2(xr[m3], xi[m3]), make_float2(xr[p], xi[p]),
                wr, wi, dr, di, rbh, ibh, G1, G2);
        xr[m3] = G1.x; xi[m3] = G1.y; xr[p] = G2.x; xi[p] = G2.y;
        rotE8(wr, wi);
      }
    }
  }
  fft8<true>(xr, xi);
  fft8<true>(xr + 8, xi + 8);
#pragma unroll
  for (int t = 0; t < 8; ++t) cxs[pA + t] = make_float2(xr[t], xi[t]);
#pragma unroll
  for (int t = 0; t < 8; ++t) cxs[pB + t] = make_float2(xr[8 + t], xi[8 + t]);
  __syncthreads();
  // ---- inv stage 2, in-place on own 16 slots
#pragma unroll
  for (int s = 0; s < 16; ++s) {
    float2 v = cxs[cb + PIDX((c2 << 7) + j2 + (s << 3))];
    xr[s] = v.x; xi[s] = v.y;
  }
  twchain<true>(xr, xi, j2, 1.0f / 128.0f);
  fft16<true>(xr, xi);
#pragma unroll
  for (int s = 0; s < 16; ++s) cxs[cb + PIDX((c2 << 7) + j2 + (s << 3))] = make_float2(xr[s], xi[s]);
  __syncthreads();
  // ---- inv stage 1 -> time samples -> bf16 pairs to global
#pragma unroll
  for (int s = 0; s < 16; ++s) {
    float2 v = cxs[cb + PIDX(j + (s << 7))];
    xr[s] = v.x; xi[s] = v.y;
  }
  twchain<true>(xr, xi, j, 1.0f / 2048.0f);
  fft16<true>(xr, xi);
#pragma unroll
  for (int s = 0; s < 16; ++s)
    o32[j + (s << 7)] = pk2(xr[s] * 0.015625f, xi[s] * 0.015625f);
}

// ---------------------------------------------------------------- gemm2
// out[b][n][c] = bn2( sum_k hb[b][k][n] * W2[c][k] )  via tr_b16 B-frags (pitched hb)
__global__ __launch_bounds__(256) void gemm2k(
    const unsigned short* __restrict__ hb, const float* __restrict__ W2,
    const float* __restrict__ g2, const float* __restrict__ b2,
    const float* __restrict__ m2, const float* __restrict__ v2,
    float* __restrict__ out) {
  __shared__ __align__(16) float poolf[8704];            // 34816 B
  unsigned short* Asw = (unsigned short*)poolf;          // [64 c][72 pitch k]
  unsigned short* Bsh = (unsigned short*)poolf + 4608;   // [k/4][n/16][4][16], 16 KB
  float* Tn = poolf;                                     // epilogue alias: [128 n][68 pitch c]
  const int n0 = blockIdx.x << 7, c0 = blockIdx.y << 6, b = blockIdx.z;
  const int tid = threadIdx.x;
  const int l = tid & 63, q = l >> 4, l16 = l & 15;
  const int wv = tid >> 6, wn2 = wv >> 1, wc2 = wv & 1;
  const int srow = tid >> 3, scol = (tid & 7) << 3;
  const unsigned bbase = ldsoff(&Bsh[0]);
  f32x4 acc[2][4];
#pragma unroll
  for (int i_ = 0; i_ < 2; ++i_)
#pragma unroll
    for (int j_ = 0; j_ < 4; ++j_) acc[i_][j_] = {0.f, 0.f, 0.f, 0.f};

  for (int kt = 0; kt < 12; ++kt) {
    const int k0 = kt << 6;
#pragma unroll
    for (int p = 0; p < 2; ++p) {
      int row = srow + (p << 5);
      const float4* sa = reinterpret_cast<const float4*>(
          &W2[(size_t)(c0 + row) * H_ + k0 + scol]);
      float4 a0 = sa[0], a1 = sa[1];
      uint4 w;
      w.x = pk2(a0.x, a0.y); w.y = pk2(a0.z, a0.w);
      w.z = pk2(a1.x, a1.y); w.w = pk2(a1.z, a1.w);
      *reinterpret_cast<uint4*>(&Asw[row * 72 + scol]) = w;
    }
#pragma unroll
    for (int p = 0; p < 4; ++p) {
      int s = tid + (p << 8);
      int k = ((s >> 6) << 2) | ((s >> 1) & 3);
      int n = (((s >> 3) & 7) << 4) | ((s & 1) << 3);
      gld16(&hb[(size_t)(b * H_ + k0 + k) * NP_ + n0 + n], &Bsh[s << 3]);
    }
    __syncthreads();
    v8bf afr[2][2];
#pragma unroll
    for (int fm = 0; fm < 2; ++fm)
#pragma unroll
      for (int ks = 0; ks < 2; ++ks)
        afr[fm][ks] = *reinterpret_cast<const v8bf*>(
            &Asw[((wc2 << 5) + (fm << 4) + l16) * 72 + (ks << 5) + (q << 3)]);
    u32x2 tr[4][2][2];
#pragma unroll
    for (int fn = 0; fn < 4; ++fn)
#pragma unroll
      for (int ks = 0; ks < 2; ++ks) {
        int nidx = (wn2 << 2) + fn;
        unsigned a = bbase + (unsigned)((l16 << 3) + (q << 11) + (ks << 13) + (nidx << 7));
        asm volatile("ds_read_b64_tr_b16 %0, %1 offset:0" : "=v"(tr[fn][ks][0]) : "v"(a));
        asm volatile("ds_read_b64_tr_b16 %0, %1 offset:1024" : "=v"(tr[fn][ks][1]) : "v"(a));
      }
    asm volatile("s_waitcnt lgkmcnt(0)" ::: "memory");
    __builtin_amdgcn_sched_barrier(0);
#pragma unroll
    for (int ks = 0; ks < 2; ++ks)
#pragma unroll
      for (int fn = 0; fn < 4; ++fn) {
        union { unsigned int u[4]; v8bf v; } bb;
        bb.u[0] = tr[fn][ks][0].x; bb.u[1] = tr[fn][ks][0].y;
        bb.u[2] = tr[fn][ks][1].x; bb.u[3] = tr[fn][ks][1].y;
#pragma unroll
        for (int fm = 0; fm < 2; ++fm)
          acc[fm][fn] = __builtin_amdgcn_mfma_f32_16x16x32_bf16(afr[fm][ks], bb.v, acc[fm][fn], 0, 0, 0);
      }
    __syncthreads();
  }
  // epilogue: BN -> Tn[n][c] (pitch 68 floats), then coalesced copy-out
#pragma unroll
  for (int fm = 0; fm < 2; ++fm) {
    int cl = (wc2 << 5) + (fm << 4) + (q << 2);
    int c4 = c0 + cl;
    float4 gv = *reinterpret_cast<const float4*>(&g2[c4]);
    float4 vv = *reinterpret_cast<const float4*>(&v2[c4]);
    float4 bv = *reinterpret_cast<const float4*>(&b2[c4]);
    float4 mv = *reinterpret_cast<const float4*>(&m2[c4]);
    float4 sc, bi;
    sc.x = gv.x * rsqrtf(vv.x + 1e-5f); bi.x = bv.x - mv.x * sc.x;
    sc.y = gv.y * rsqrtf(vv.y + 1e-5f); bi.y = bv.y - mv.y * sc.y;
    sc.z = gv.z * rsqrtf(vv.z + 1e-5f); bi.z = bv.z - mv.z * sc.z;
    sc.w = gv.w * rsqrtf(vv.w + 1e-5f); bi.w = bv.w - mv.w * sc.w;
#pragma unroll
    for (int fn = 0; fn < 4; ++fn) {
      int nl = (wn2 << 6) + (fn << 4) + l16;
      float4 o;
      o.x = acc[fm][fn][0] * sc.x + bi.x;
      o.y = acc[fm][fn][1] * sc.y + bi.y;
      o.z = acc[fm][fn][2] * sc.z + bi.z;
      o.w = acc[fm][fn][3] * sc.w + bi.w;
      *reinterpret_cast<float4*>(&Tn[nl * 68 + cl]) = o;
    }
  }
  __syncthreads();
  {
    const int rq = tid >> 4, ch = (tid & 15) << 2;
#pragma unroll
    for (int p = 0; p < 8; ++p) {
      int r = (p << 4) + rq;
      float4 v = *reinterpret_cast<const float4*>(&Tn[r * 68 + ch]);
      *reinterpret_cast<float4*>(&out[(size_t)(b * N_ + n0 + r) * C_ + c0 + ch]) = v;
    }
  }
}

// ---------------------------------------------------------------- launch
extern "C" void kernel_launch(void* const* d_in, const int* in_sizes, int n_in,
                              void* d_out, int out_size, void* d_ws, size_t ws_size,
                              hipStream_t stream) {
  const float* x  = (const float*)d_in[0];
  const float* W1 = (const float*)d_in[1];
  const float* g1 = (const float*)d_in[2];
  const float* b1 = (const float*)d_in[3];
  const float* m1 = (const float*)d_in[4];
  const float* v1 = (const float*)d_in[5];
  const float* Rm = (const float*)d_in[6];
  const float* Im = (const float*)d_in[7];
  const float* rb = (const float*)d_in[8];
  const float* ib = (const float*)d_in[9];
  const float* W2 = (const float*)d_in[10];
  const float* g2 = (const float*)d_in[11];
  const float* b2 = (const float*)d_in[12];
  const float* m2 = (const float*)d_in[13];
  const float* v2 = (const float*)d_in[14];
  float* out = (float*)d_out;

  unsigned short* hb = (unsigned short*)d_ws;   // [B][H][NP_] bf16 pitched, 53.5 MB

  gemm1k<<<dim3(32, 6, 8), 256, 0, stream>>>(x, W1, g1, b1, m1, v1, hb);
  fftmixk<<<dim3(384, 8), 256, 0, stream>>>(hb, Rm, Im, rb, ib);
  gemm2k<<<dim3(32, 3, 8), 256, 0, stream>>>(hb, W2, g2, b2, m2, v2, out);
}

// Round 10
// 192.129 us; speedup vs baseline: 1.0724x; 1.0724x over previous
//
#include <hip/hip_runtime.h>

typedef float f32x4 __attribute__((ext_vector_type(4)));
typedef __bf16 v8bf __attribute__((ext_vector_type(8)));
typedef unsigned int u32x2 __attribute__((ext_vector_type(2)));

#define B_ 8
#define N_ 4096
#define C_ 192
#define H_ 768

__device__ __forceinline__ unsigned short f2bf(float f) {
  unsigned int u = __float_as_uint(f);
  u += 0x7FFFu + ((u >> 16) & 1u);          // RNE
  return (unsigned short)(u >> 16);
}
__device__ __forceinline__ unsigned int pk2(float lo, float hi) {
  return (unsigned int)f2bf(lo) | ((unsigned int)f2bf(hi) << 16);
}
__device__ __forceinline__ void unpk(unsigned int w, float& a, float& b) {
  a = __uint_as_float(w << 16);
  b = __uint_as_float(w & 0xFFFF0000u);
}

#define LDS_AS(p) ((__attribute__((address_space(3))) unsigned int*)(void*)(p))
__device__ __forceinline__ void gld16(const void* g, void* l) {
  __builtin_amdgcn_global_load_lds((const __attribute__((address_space(1))) unsigned int*)g,
                                   LDS_AS(l), 16, 0, 0);
}
__device__ __forceinline__ unsigned ldsoff(const void* p) {
  return (unsigned)(size_t)((__attribute__((address_space(3))) char*)(void*)p);
}

// ---------------------------------------------------------------- cvt fp32 -> bf16 (x, W1, W2)
__global__ __launch_bounds__(256) void cvtk(
    const float* __restrict__ x, const float* __restrict__ w1, const float* __restrict__ w2,
    unsigned short* __restrict__ xb, unsigned short* __restrict__ w1b,
    unsigned short* __restrict__ w2b) {
  int i = blockIdx.x * 256 + threadIdx.x;   // 823296 slots of 8 elems
  const float* src; unsigned short* dst; int off;
  if (i < 786432)      { src = x;  dst = xb;  off = i; }
  else if (i < 804864) { src = w1; dst = w1b; off = i - 786432; }
  else                 { src = w2; dst = w2b; off = i - 804864; }
  const float4* s4 = reinterpret_cast<const float4*>(src + (size_t)off * 8);
  float4 a = s4[0], b = s4[1];
  uint4 o;
  o.x = pk2(a.x, a.y); o.y = pk2(a.z, a.w);
  o.z = pk2(b.x, b.y); o.w = pk2(b.z, b.w);
  *reinterpret_cast<uint4*>(dst + (size_t)off * 8) = o;
}

// ---------------------------------------------------------------- gemm1
// hb[b][h][n] = relu(bn1( sum_c xb[b][n][c] * W1b[h][c] ))   (bf16 out)
// 128x128xBK64, dbuf 1-deep prefetch, lane-linear gld16 staging + chunk-XOR swizzle.
// LDS 64KB (A0,A1 16K; B0,B1 16K), 2 blocks/CU. LDS-transpose epilogue.
__global__ __launch_bounds__(256) void gemm1k(
    const unsigned short* __restrict__ xb, const unsigned short* __restrict__ W1b,
    const float* __restrict__ g1, const float* __restrict__ b1,
    const float* __restrict__ m1, const float* __restrict__ v1,
    unsigned short* __restrict__ hb) {
  __shared__ __align__(16) unsigned short pool[32768];   // 64 KB
  char* LB = (char*)pool;            // A0@0, A1@16K, B0@32K, B1@48K
  unsigned short* Ts = pool;         // epilogue alias [128 h][136 pitch n] (34.8KB)
  const int n0 = blockIdx.x << 7, h0 = blockIdx.y << 7, b = blockIdx.z;
  const int tid = threadIdx.x;
  const int l = tid & 63, q = l >> 4, l16 = l & 15;
  const int wv = tid >> 6, wr = wv >> 1, wc = wv & 1;
  f32x4 acc[4][4];
#pragma unroll
  for (int i_ = 0; i_ < 4; ++i_)
#pragma unroll
    for (int j_ = 0; j_ < 4; ++j_) acc[i_][j_] = {0.f, 0.f, 0.f, 0.f};

  auto STAGE = [&](int kt, int nxt) {
    const int k0 = kt << 6;
#pragma unroll
    for (int p = 0; p < 4; ++p) {
      int s = tid + (p << 8);                 // 0..1023 = [128 rows][8 chunks]
      int r = s >> 3, cs = s & 7, csl = cs ^ (r & 7);
      gld16(&xb[(size_t)(b * N_ + n0 + r) * C_ + k0 + (csl << 3)],
            LB + ((unsigned)nxt << 14) + ((unsigned)s << 4));
      gld16(&W1b[(size_t)(h0 + r) * C_ + k0 + (csl << 3)],
            LB + 32768u + ((unsigned)nxt << 14) + ((unsigned)s << 4));
    }
  };

  STAGE(0, 0);
  __syncthreads();
  int cur = 0;
  for (int kt = 0; kt < 3; ++kt) {
    if (kt < 2) STAGE(kt + 1, cur ^ 1);       // prefetch flies during compute
    const unsigned aL = (unsigned)cur << 14;
    const unsigned bL = 32768u + ((unsigned)cur << 14);
#pragma unroll
    for (int ks = 0; ks < 2; ++ks) {
      const unsigned jo = ((unsigned)ks << 6) | ((unsigned)q << 4);
      v8bf av[4], bv[4];
#pragma unroll
      for (int f = 0; f < 4; ++f) {
        int rowA = (wr << 6) + (f << 4) + l16;
        av[f] = *reinterpret_cast<const v8bf*>(LB + aL + rowA * 128 + (jo ^ ((rowA & 7) << 4)));
        int rowB = (wc << 6) + (f << 4) + l16;
        bv[f] = *reinterpret_cast<const v8bf*>(LB + bL + rowB * 128 + (jo ^ ((rowB & 7) << 4)));
      }
#pragma unroll
      for (int fm = 0; fm < 4; ++fm)
#pragma unroll
        for (int fn = 0; fn < 4; ++fn)
          acc[fm][fn] = __builtin_amdgcn_mfma_f32_16x16x32_bf16(av[fm], bv[fn], acc[fm][fn], 0, 0, 0);
    }
    __syncthreads();                          // drains prefetch gld16s too
    cur ^= 1;
  }
  // epilogue: BN+ReLU -> bf16 into Ts[h][n] (pitch 136), then coalesced copy-out
#pragma unroll
  for (int fn = 0; fn < 4; ++fn) {
    int hl = (wc << 6) + (fn << 4) + l16;
    int hh = h0 + hl;
    float s = g1[hh] * rsqrtf(v1[hh] + 1e-5f);
    float bias = b1[hh] - m1[hh] * s;
#pragma unroll
    for (int fm = 0; fm < 4; ++fm) {
      int nl = (wr << 6) + (fm << 4) + (q << 2);
      ushort4 o;
      o.x = f2bf(fmaxf(acc[fm][fn][0] * s + bias, 0.f));
      o.y = f2bf(fmaxf(acc[fm][fn][1] * s + bias, 0.f));
      o.z = f2bf(fmaxf(acc[fm][fn][2] * s + bias, 0.f));
      o.w = f2bf(fmaxf(acc[fm][fn][3] * s + bias, 0.f));
      *reinterpret_cast<ushort4*>(&Ts[hl * 136 + nl]) = o;
    }
  }
  __syncthreads();
  {
    const int rq = tid >> 4, ch = (tid & 15) << 3;
#pragma unroll
    for (int p = 0; p < 8; ++p) {
      int r = (p << 4) + rq;
      uint4 v = *reinterpret_cast<const uint4*>(&Ts[r * 136 + ch]);
      *reinterpret_cast<uint4*>(&hb[((size_t)(b * H_ + h0 + r) << 12) + n0 + ch]) = v;
    }
  }
}

// ---------------------------------------------------------------- FFT pieces
template <bool INV>
__device__ __forceinline__ void dft4(float& ar, float& ai, float& br, float& bi,
                                     float& cr, float& ci, float& dr, float& di) {
  float t0r = ar + cr, t0i = ai + ci;
  float t1r = ar - cr, t1i = ai - ci;
  float t2r = br + dr, t2i = bi + di;
  float t3r = br - dr, t3i = bi - di;
  ar = t0r + t2r; ai = t0i + t2i;
  cr = t0r - t2r; ci = t0i - t2i;
  if (!INV) { br = t1r + t3i; bi = t1i - t3r; dr = t1r - t3i; di = t1i + t3r; }
  else      { br = t1r - t3i; bi = t1i + t3r; dr = t1r + t3i; di = t1i - t3r; }
}
template <bool INV>
__device__ __forceinline__ void twc(float& xr, float& xi, float wr, float wi) {
  float iw = INV ? -wi : wi;
  float nr = xr * wr - xi * iw;
  xi = xr * iw + xi * wr;
  xr = nr;
}
template <bool INV>
__device__ __forceinline__ void fft16(float* xr, float* xi) {
#pragma unroll
  for (int j = 0; j < 4; ++j)
    dft4<INV>(xr[j], xi[j], xr[j + 4], xi[j + 4], xr[j + 8], xi[j + 8], xr[j + 12], xi[j + 12]);
  const float C1 = 0.9238795325112867f, S1 = -0.3826834323650898f;
  const float C2 = 0.7071067811865476f, S2 = -0.7071067811865476f;
  twc<INV>(xr[5], xi[5], C1, S1);
  twc<INV>(xr[6], xi[6], C2, S2);
  twc<INV>(xr[9], xi[9], C2, S2);
  twc<INV>(xr[7], xi[7], -S1, -C1);
  twc<INV>(xr[13], xi[13], -S1, -C1);
  twc<INV>(xr[10], xi[10], 0.f, -1.f);
  twc<INV>(xr[11], xi[11], -C2, S2);
  twc<INV>(xr[14], xi[14], -C2, S2);
  twc<INV>(xr[15], xi[15], -C1, -S1);
  float yr[16], yi[16];
#pragma unroll
  for (int k = 0; k < 4; ++k) {
    float ar = xr[4 * k], ai = xi[4 * k], br = xr[4 * k + 1], bi = xi[4 * k + 1];
    float cr = xr[4 * k + 2], ci = xi[4 * k + 2], dr = xr[4 * k + 3], di = xi[4 * k + 3];
    dft4<INV>(ar, ai, br, bi, cr, ci, dr, di);
    yr[k] = ar; yi[k] = ai; yr[k + 4] = br; yi[k + 4] = bi;
    yr[k + 8] = cr; yi[k + 8] = ci; yr[k + 12] = dr; yi[k + 12] = di;
  }
#pragma unroll
  for (int qq = 0; qq < 16; ++qq) { xr[qq] = yr[qq]; xi[qq] = yi[qq]; }
}
template <bool INV>
__device__ __forceinline__ void fft8(float* xr, float* xi) {
  float er[4] = {xr[0], xr[2], xr[4], xr[6]}, ei[4] = {xi[0], xi[2], xi[4], xi[6]};
  float o_r[4] = {xr[1], xr[3], xr[5], xr[7]}, o_i[4] = {xi[1], xi[3], xi[5], xi[7]};
  dft4<INV>(er[0], ei[0], er[1], ei[1], er[2], ei[2], er[3], ei[3]);
  dft4<INV>(o_r[0], o_i[0], o_r[1], o_i[1], o_r[2], o_i[2], o_r[3], o_i[3]);
  const float c = 0.7071067811865476f;
  twc<INV>(o_r[1], o_i[1], c, -c);      // W8^1
  twc<INV>(o_r[2], o_i[2], 0.f, -1.f);  // W8^2
  twc<INV>(o_r[3], o_i[3], -c, -c);     // W8^3
#pragma unroll
  for (int k = 0; k < 4; ++k) {
    xr[k] = er[k] + o_r[k]; xi[k] = ei[k] + o_i[k];
    xr[k + 4] = er[k] - o_r[k]; xi[k + 4] = ei[k] - o_i[k];
  }
}
template <bool INV>
__device__ __forceinline__ void twchain(float* xr, float* xi, int j, float invL) {
  float ang = -6.283185307179586f * (float)j * invL;
  if (INV) ang = -ang;
  float s1, c1;
  __sincosf(ang, &s1, &c1);
  float wr = c1, wi = s1;
#pragma unroll
  for (int r2 = 1; r2 < 16; ++r2) {
    float nr = xr[r2] * wr - xi[r2] * wi;
    xi[r2] = xr[r2] * wi + xi[r2] * wr;
    xr[r2] = nr;
    float t2 = wr * c1 - wi * s1;
    wi = wr * s1 + wi * c1;
    wr = t2;
  }
}

// one packed bin-pair of the frequency-domain op:
// inputs Zk=Z[k], Zp=Z[(2048-k)&2047], W=e^{-2pi i k/4096}; outputs G[k], G[2048-k]
__device__ __forceinline__ void mixpair(float2 Zk, float2 Zp, float wr, float wi,
                                        float dr, float di, float rbh, float ibh,
                                        float2& G1, float2& G2) {
  const float sc = 0.015625f;
  float Er = 0.5f * (Zk.x + Zp.x), Ei = 0.5f * (Zk.y - Zp.y);
  float Or = 0.5f * (Zk.y + Zp.y), Oi = 0.5f * (Zp.x - Zk.x);
  float WOr = wr * Or - wi * Oi, WOi = wr * Oi + wi * Or;
  float X1r = Er + WOr, X1i = Ei + WOi;   // bin k
  float X2r = Er - WOr, X2i = Ei - WOi;   // bin k+2048
  float p1 = dr * X1r * sc, p2 = di * X1i * sc, p3 = dr * X1i * sc, p4 = di * X1r * sc;
  float y1r = fmaxf(p1 - p2 + rbh, 0.f), y1i = fmaxf(p3 + p4 + ibh, 0.f);   // Y[k]
  float y4r = fmaxf(p1 + p2 + rbh, 0.f), y4i = fmaxf(p4 - p3 + ibh, 0.f);   // Y[4096-k]
  float q1 = dr * X2r * sc, q2 = di * X2i * sc, q3 = dr * X2i * sc, q4 = di * X2r * sc;
  float y2r = fmaxf(q1 - q2 + rbh, 0.f), y2i = fmaxf(q3 + q4 + ibh, 0.f);   // Y[k+2048]
  float y3r = fmaxf(q1 + q2 + rbh, 0.f), y3i = fmaxf(q4 - q3 + ibh, 0.f);   // Y[2048-k]
  float Hkr = 0.5f * (y1r + y4r), Hki = 0.5f * (y1i - y4i);   // H[k]
  float H2r = 0.5f * (y2r + y3r), H2i = 0.5f * (y2i - y3i);   // H[k+2048]
  float Sr = Hkr + H2r, Si = Hki + H2i;
  float Dr = Hkr - H2r, Di = Hki - H2i;
  float P = wi * Dr - wr * Di, Q = wr * Dr + wi * Di;
  G1 = make_float2(Sr + P, Si + Q);
  G2 = make_float2(Sr - P, Q - Si);
}

// ---------------------------------------------------------------- fftmix (R5 structure, 66us)
#define PIDX(i) ((i) + ((i) >> 4))
__global__ __launch_bounds__(256) void fftmixk(
    unsigned short* __restrict__ hb, const float* __restrict__ Rm,
    const float* __restrict__ Im, const float* __restrict__ rb,
    const float* __restrict__ ib) {
  __shared__ float2 cxs[4352];              // 2 channels x 2176 padded float2
  const int b = blockIdx.y;
  const int tid = threadIdx.x;
  const int ch = tid >> 7, j = tid & 127;
  const int h = (blockIdx.x << 1) | ch;
  const int cb = ch * 2176;
  unsigned short* sig = hb + ((size_t)(b * H_ + h) << 12);
  const unsigned int* sig32 = reinterpret_cast<const unsigned int*>(sig);
  unsigned int* o32 = reinterpret_cast<unsigned int*>(sig);

  float xr[16], xi[16];
  // ---- forward stage 1 (L=2048, radix16 stride128): z[m]=h[2m]+i h[2m+1]
#pragma unroll
  for (int s = 0; s < 16; ++s) {
    unsigned int w = sig32[j + (s << 7)];
    unpk(w, xr[s], xi[s]);
  }
  fft16<false>(xr, xi);
  twchain<false>(xr, xi, j, 1.0f / 2048.0f);
#pragma unroll
  for (int s = 0; s < 16; ++s) cxs[cb + PIDX(j + (s << 7))] = make_float2(xr[s], xi[s]);
  __syncthreads();
  // ---- forward stage 2 (size128, radix16 stride8)
  const int c2 = j >> 3, j2 = j & 7;
#pragma unroll
  for (int s = 0; s < 16; ++s) {
    float2 v = cxs[cb + PIDX((c2 << 7) + j2 + (s << 3))];
    xr[s] = v.x; xi[s] = v.y;
  }
  fft16<false>(xr, xi);
  twchain<false>(xr, xi, j2, 1.0f / 128.0f);
#pragma unroll
  for (int s = 0; s < 16; ++s) cxs[cb + PIDX((c2 << 7) + j2 + (s << 3))] = make_float2(xr[s], xi[s]);
  __syncthreads();
  // ---- forward stage 3 (radix8 stride1): read positional, write natural-k
#pragma unroll
  for (int gg = 0; gg < 2; ++gg) {
    int g = j + (gg << 7);
#pragma unroll
    for (int s = 0; s < 8; ++s) {
      float2 v = cxs[cb + PIDX((g << 3) + s)];
      xr[(gg << 3) + s] = v.x; xi[(gg << 3) + s] = v.y;
    }
  }
  __syncthreads();
#pragma unroll
  for (int gg = 0; gg < 2; ++gg) {
    int g = j + (gg << 7);
    fft8<false>(&xr[gg << 3], &xi[gg << 3]);
    int kb = (g >> 4) + ((g & 15) << 4);
#pragma unroll
    for (int s = 0; s < 8; ++s)
      cxs[cb + PIDX(kb + (s << 8))] = make_float2(xr[(gg << 3) + s], xi[(gg << 3) + s]);
  }
  __syncthreads();
  // ---- mix: pairs (k, 2048-k), k = 8j+u
  {
    const float dr = Rm[(size_t)h * (H_ + 1)];
    const float di = Im[(size_t)h * (H_ + 1)];
    const float rbh = rb[h], ibh = ib[h];
    float sn, cs;
    __sincosf(3.14159265358979f * (float)j / 256.0f, &sn, &cs);
    float wr = cs, wi = -sn;                       // W^(8j)
    const float WSR = 0.9999988234517019f, WSI = -0.0015339801862847655f;
#pragma unroll
    for (int u = 0; u < 8; ++u) {
      int k = (j << 3) + u;
      int kp = (2048 - k) & 2047;
      float2 Zk = cxs[cb + PIDX(k)];
      float2 Zp = cxs[cb + PIDX(kp)];
      float2 G1, G2;
      mixpair(Zk, Zp, wr, wi, dr, di, rbh, ibh, G1, G2);
      cxs[cb + PIDX(k)] = G1;
      cxs[cb + PIDX(kp)] = G2;
      float nwr = wr * WSR - wi * WSI;
      wi = wr * WSI + wi * WSR;
      wr = nwr;
    }
    if (j == 0) {   // bin 1024 self-pair, W^1024 = (0,-1)
      float2 Zs = cxs[cb + PIDX(1024)];
      float2 G1, G2;
      mixpair(Zs, Zs, 0.f, -1.f, dr, di, rbh, ibh, G1, G2);
      cxs[cb + PIDX(1024)] = G1;
    }
  }
  __syncthreads();
  // ---- inverse stage 3: read natural-k, write positional
#pragma unroll
  for (int gg = 0; gg < 2; ++gg) {
    int g = j + (gg << 7);
    int kb = (g >> 4) + ((g & 15) << 4);
#pragma unroll
    for (int s = 0; s < 8; ++s) {
      float2 v = cxs[cb + PIDX(kb + (s << 8))];
      xr[(gg << 3) + s] = v.x; xi[(gg << 3) + s] = v.y;
    }
  }
  __syncthreads();
#pragma unroll
  for (int gg = 0; gg < 2; ++gg) {
    int g = j + (gg << 7);
    fft8<true>(&xr[gg << 3], &xi[gg << 3]);
#pragma unroll
    for (int s = 0; s < 8; ++s)
      cxs[cb + PIDX((g << 3) + s)] = make_float2(xr[(gg << 3) + s], xi[(gg << 3) + s]);
  }
  __syncthreads();
  // ---- inverse stage 2
#pragma unroll
  for (int s = 0; s < 16; ++s) {
    float2 v = cxs[cb + PIDX((c2 << 7) + j2 + (s << 3))];
    xr[s] = v.x; xi[s] = v.y;
  }
  twchain<true>(xr, xi, j2, 1.0f / 128.0f);
  fft16<true>(xr, xi);
#pragma unroll
  for (int s = 0; s < 16; ++s) cxs[cb + PIDX((c2 << 7) + j2 + (s << 3))] = make_float2(xr[s], xi[s]);
  __syncthreads();
  // ---- inverse stage 1 -> time samples -> bf16 pairs to global
#pragma unroll
  for (int s = 0; s < 16; ++s) {
    float2 v = cxs[cb + PIDX(j + (s << 7))];
    xr[s] = v.x; xi[s] = v.y;
  }
  twchain<true>(xr, xi, j, 1.0f / 2048.0f);
  fft16<true>(xr, xi);
#pragma unroll
  for (int s = 0; s < 16; ++s)
    o32[j + (s << 7)] = pk2(xr[s] * 0.015625f, xi[s] * 0.015625f);
}

// ---------------------------------------------------------------- gemm2
// out[b][n][c] = bn2( sum_k hb[b][k][n] * W2b[c][k] )
// dbuf A+B, all-gld16 (lane-linear), 1-deep prefetch, tr_b16 B-frags,
// swizzled linear A, LDS-transpose epilogue. 48KB LDS, 3 blocks/CU.
__global__ __launch_bounds__(256) void gemm2k(
    const unsigned short* __restrict__ hb, const unsigned short* __restrict__ W2b,
    const float* __restrict__ g2, const float* __restrict__ b2,
    const float* __restrict__ m2, const float* __restrict__ v2,
    float* __restrict__ out) {
  __shared__ __align__(16) unsigned short pool[24576];   // 48 KB: B0,B1 16K each; A0,A1 8K each
  char* LB = (char*)pool;
  float* Tn = (float*)pool;                              // epilogue alias [128 n][68 pitch c]
  const int n0 = blockIdx.x << 7, c0 = blockIdx.y << 6, b = blockIdx.z;
  const int tid = threadIdx.x;
  const int l = tid & 63, q = l >> 4, l16 = l & 15;
  const int wv = tid >> 6, wn2 = wv >> 1, wc2 = wv & 1;
  const unsigned lbase = ldsoff(LB);
  f32x4 acc[2][4];
#pragma unroll
  for (int i_ = 0; i_ < 2; ++i_)
#pragma unroll
    for (int j_ = 0; j_ < 4; ++j_) acc[i_][j_] = {0.f, 0.f, 0.f, 0.f};

  auto STAGE = [&](int kt, int nxt) {
    const int k0 = kt << 6;
#pragma unroll
    for (int p = 0; p < 4; ++p) {   // B subtiled [k/4][n/16][4][16]
      int s = tid + (p << 8);
      int k = ((s >> 6) << 2) | ((s >> 1) & 3);
      int n = (((s >> 3) & 7) << 4) | ((s & 1) << 3);
      gld16(&hb[((size_t)(b * H_ + k0 + k) << 12) + n0 + n], LB + (nxt << 14) + (s << 4));
    }
#pragma unroll
    for (int p = 0; p < 2; ++p) {   // A [64 c][8 chunks] swizzled
      int s = tid + (p << 8);
      int r = s >> 3, cs = s & 7, csl = cs ^ (r & 7);
      gld16(&W2b[(size_t)(c0 + r) * H_ + k0 + (csl << 3)], LB + 32768 + (nxt << 13) + (s << 4));
    }
  };

  STAGE(0, 0);
  __syncthreads();
  int cur = 0;
  for (int kt = 0; kt < 12; ++kt) {
    if (kt < 11) STAGE(kt + 1, cur ^ 1);      // loads fly during compute below
    const unsigned ab = 32768u + ((unsigned)cur << 13);
    const unsigned bb = (unsigned)cur << 14;
    v8bf afr[2][2];
#pragma unroll
    for (int fm = 0; fm < 2; ++fm)
#pragma unroll
      for (int ks = 0; ks < 2; ++ks) {
        int row = (wc2 << 5) + (fm << 4) + l16;
        unsigned off = ab + row * 128 + (((ks << 6) | (q << 4)) ^ ((row & 7) << 4));
        afr[fm][ks] = *reinterpret_cast<const v8bf*>(LB + off);
      }
    u32x2 tr[4][2][2];
#pragma unroll
    for (int fn = 0; fn < 4; ++fn)
#pragma unroll
      for (int ks = 0; ks < 2; ++ks) {
        int nidx = (wn2 << 2) + fn;
        unsigned a = lbase + bb + (unsigned)((l16 << 3) + (q << 11) + (ks << 13) + (nidx << 7));
        asm volatile("ds_read_b64_tr_b16 %0, %1 offset:0" : "=v"(tr[fn][ks][0]) : "v"(a));
        asm volatile("ds_read_b64_tr_b16 %0, %1 offset:1024" : "=v"(tr[fn][ks][1]) : "v"(a));
      }
    asm volatile("s_waitcnt lgkmcnt(0)" ::: "memory");
    __builtin_amdgcn_sched_barrier(0);
#pragma unroll
    for (int ks = 0; ks < 2; ++ks)
#pragma unroll
      for (int fn = 0; fn < 4; ++fn) {
        union { unsigned int u[4]; v8bf v; } bbv;
        bbv.u[0] = tr[fn][ks][0].x; bbv.u[1] = tr[fn][ks][0].y;
        bbv.u[2] = tr[fn][ks][1].x; bbv.u[3] = tr[fn][ks][1].y;
#pragma unroll
        for (int fm = 0; fm < 2; ++fm)
          acc[fm][fn] = __builtin_amdgcn_mfma_f32_16x16x32_bf16(afr[fm][ks], bbv.v, acc[fm][fn], 0, 0, 0);
      }
    __syncthreads();                           // drains prefetch gld16s too
    cur ^= 1;
  }
  // epilogue: BN -> Tn[n][c] (pitch 68 floats), then coalesced copy-out
#pragma unroll
  for (int fm = 0; fm < 2; ++fm) {
    int cl = (wc2 << 5) + (fm << 4) + (q << 2);
    int c4 = c0 + cl;
    float4 gv = *reinterpret_cast<const float4*>(&g2[c4]);
    float4 vv = *reinterpret_cast<const float4*>(&v2[c4]);
    float4 bv = *reinterpret_cast<const float4*>(&b2[c4]);
    float4 mv = *reinterpret_cast<const float4*>(&m2[c4]);
    float4 sc, bi;
    sc.x = gv.x * rsqrtf(vv.x + 1e-5f); bi.x = bv.x - mv.x * sc.x;
    sc.y = gv.y * rsqrtf(vv.y + 1e-5f); bi.y = bv.y - mv.y * sc.y;
    sc.z = gv.z * rsqrtf(vv.z + 1e-5f); bi.z = bv.z - mv.z * sc.z;
    sc.w = gv.w * rsqrtf(vv.w + 1e-5f); bi.w = bv.w - mv.w * sc.w;
#pragma unroll
    for (int fn = 0; fn < 4; ++fn) {
      int nl = (wn2 << 6) + (fn << 4) + l16;
      float4 o;
      o.x = acc[fm][fn][0] * sc.x + bi.x;
      o.y = acc[fm][fn][1] * sc.y + bi.y;
      o.z = acc[fm][fn][2] * sc.z + bi.z;
      o.w = acc[fm][fn][3] * sc.w + bi.w;
      *reinterpret_cast<float4*>(&Tn[nl * 68 + cl]) = o;
    }
  }
  __syncthreads();
  {
    const int rq = tid >> 4, ch = (tid & 15) << 2;
#pragma unroll
    for (int p = 0; p < 8; ++p) {
      int r = (p << 4) + rq;
      float4 v = *reinterpret_cast<const float4*>(&Tn[r * 68 + ch]);
      *reinterpret_cast<float4*>(&out[(size_t)(b * N_ + n0 + r) * C_ + c0 + ch]) = v;
    }
  }
}

// ---------------------------------------------------------------- launch
extern "C" void kernel_launch(void* const* d_in, const int* in_sizes, int n_in,
                              void* d_out, int out_size, void* d_ws, size_t ws_size,
                              hipStream_t stream) {
  const float* x  = (const float*)d_in[0];
  const float* W1 = (const float*)d_in[1];
  const float* g1 = (const float*)d_in[2];
  const float* b1 = (const float*)d_in[3];
  const float* m1 = (const float*)d_in[4];
  const float* v1 = (const float*)d_in[5];
  const float* Rm = (const float*)d_in[6];
  const float* Im = (const float*)d_in[7];
  const float* rb = (const float*)d_in[8];
  const float* ib = (const float*)d_in[9];
  const float* W2 = (const float*)d_in[10];
  const float* g2 = (const float*)d_in[11];
  const float* b2 = (const float*)d_in[12];
  const float* m2 = (const float*)d_in[13];
  const float* v2 = (const float*)d_in[14];
  float* out = (float*)d_out;

  unsigned short* hb  = (unsigned short*)d_ws;          // [B][H][N] bf16, 50.33 MB
  unsigned short* xb  = hb + (size_t)25165824;          // [B][N][C] bf16, 12.58 MB
  unsigned short* W1b = xb + (size_t)6291456;           // [H][C] bf16
  unsigned short* W2b = W1b + (size_t)147456;           // [C][H] bf16

  cvtk<<<3216, 256, 0, stream>>>(x, W1, W2, xb, W1b, W2b);
  gemm1k<<<dim3(32, 6, 8), 256, 0, stream>>>(xb, W1b, g1, b1, m1, v1, hb);
  fftmixk<<<dim3(384, 8), 256, 0, stream>>>(hb, Rm, Im, rb, ib);
  gemm2k<<<dim3(32, 3, 8), 256, 0, stream>>>(hb, W2b, g2, b2, m2, v2, out);
}